// Round 21
// baseline (3917.562 us; speedup 1.0000x reference)
//
#include <hip/hip_runtime.h>

#define BATCH   16
#define NPTS    32768
#define NPOINT  2048
#define C_FEAT  128
#define NSEG    1024          // 32 Morton-consecutive points per segment
#define NTH     1024
#define NW      16

// ===========================================================================
// Round 21 = round 20 with the LDS overflow fixed (166KB > 160KB limit):
// the ext staging now lives in dmin[0..3*NSEG) BEFORE dmin is initialized
// (read into owner-thread registers, barrier, then dmin <- 1e10).
// Total LDS ~150KB. Steady-state loop identical to r20's design:
//  (1) bbox in owner-thread registers; cand[3][NSEG] (exact f32 candidate
//      coords per seg) gives the winner centroid from LDS (~40cy) instead of
//      a serial broadcast L2 load (~250cy).
//  (2) phase C 4/2/1-way unroll tiers (4 load+reduce chains in flight).
// Exactness invariants unchanged (r16-r19 verified, absmax 0): skip seg only
// if r2*0.999 > cmax with provably-enclosing bbox (+2ulp ext nudge);
// update = r7-VERIFIED fmaf(dz,dz,fmaf(dy,dy,dx*dx)); u64 pack-max =
// (max cmax, tie -> min ORIGINAL idx) == np.argmax first-occurrence;
// scatter-order-independent; cand writes seg-disjoint + barrier-separated.
// ws: [fps_idx 128KB @0][pts 8MB @1MB]
// ===========================================================================

__device__ __forceinline__ unsigned part4(unsigned v) {
  return (v & 1u) | ((v & 2u) << 2) | ((v & 4u) << 4) | ((v & 8u) << 6);
}
__device__ __forceinline__ int morton(float x, float y, float z) {
  const unsigned qx = (unsigned)min(15, max(0, (int)((x + 4.0f) * 2.0f)));
  const unsigned qy = (unsigned)min(15, max(0, (int)((y + 4.0f) * 2.0f)));
  const unsigned qz = (unsigned)min(15, max(0, (int)((z + 4.0f) * 2.0f)));
  return (int)(part4(qx) | (part4(qy) << 1) | (part4(qz) << 2));
}

__device__ __forceinline__ unsigned long long u64max(unsigned long long a,
                                                     unsigned long long b) {
  return a > b ? a : b;
}
__device__ __forceinline__ unsigned long long shflxor_u64(
    unsigned long long v, int off) {
  const unsigned lo = (unsigned)v, hi = (unsigned)(v >> 32);
  const unsigned olo = (unsigned)__shfl_xor((int)lo, off);
  const unsigned ohi = (unsigned)__shfl_xor((int)hi, off);
  return ((unsigned long long)ohi << 32) | olo;
}

// ---------------------------------------------------------------------------
// Morton counting sort: pts[pos] = (x,y,z,bitcast(origidx)) in sorted order.
// ---------------------------------------------------------------------------
__global__ __launch_bounds__(NTH) void sort_kernel(
    const float* __restrict__ xyz, float4* __restrict__ pts) {
  const int b = blockIdx.x, t = threadIdx.x, lane = t & 63;
  const float* __restrict__ base = xyz + (size_t)b * NPTS * 3;
  __shared__ unsigned bins[4096];
  __shared__ unsigned wsum[NW];

  for (int i = t; i < 4096; i += NTH) bins[i] = 0u;
  __syncthreads();
  for (int k = 0; k < 32; ++k) {
    const int p = k * NTH + t;
    atomicAdd(&bins[morton(base[p*3], base[p*3+1], base[p*3+2])], 1u);
  }
  __syncthreads();

  unsigned c0 = bins[4*t], c1 = bins[4*t+1], c2 = bins[4*t+2], c3 = bins[4*t+3];
  const unsigned mysum = c0 + c1 + c2 + c3;
  unsigned acc = mysum;
#pragma unroll
  for (int d = 1; d < 64; d <<= 1) {
    unsigned n = __shfl_up(acc, d);
    if (lane >= d) acc += n;
  }
  if (lane == 63) wsum[t >> 6] = acc;
  __syncthreads();
  unsigned woff = 0;
  for (int w = 0; w < (t >> 6); ++w) woff += wsum[w];
  unsigned run = woff + acc - mysum;
  bins[4*t]   = run; run += c0;
  bins[4*t+1] = run; run += c1;
  bins[4*t+2] = run; run += c2;
  bins[4*t+3] = run;
  __syncthreads();

  float4* __restrict__ pb = pts + (size_t)b * NPTS;
  for (int k = 0; k < 32; ++k) {
    const int p = k * NTH + t;
    const float x = base[p*3], y = base[p*3+1], z = base[p*3+2];
    const unsigned pos = atomicAdd(&bins[morton(x, y, z)], 1u);
    pb[pos] = make_float4(x, y, z, __int_as_float(p));
  }
}

// ---------------------------------------------------------------------------
// Work-shared lazy FPS, 32-pt half-wave segments, register bboxes,
// LDS candidate coords. One block per batch; 3 barriers/step.
// ---------------------------------------------------------------------------
__global__ __launch_bounds__(NTH) void fps_kernel(
    const float4* __restrict__ pts_g, int* __restrict__ fps_idx) {
  const int b = blockIdx.x, t = threadIdx.x, lane = t & 63, w = t >> 6;
  const int hw = t >> 5, hl = t & 31;            // 32 half-waves of 32 lanes
  const float4* __restrict__ P = pts_g + (size_t)b * NPTS;

  __shared__ float              dmin[NPTS];      // 128 KB (ext staging @init)
  __shared__ unsigned long long pack[NSEG];      // 8 KB
  __shared__ float              cand[3][NSEG];   // 12 KB (cen staging @init)
  __shared__ unsigned long long s_red[2][8];     // 128 B
  __shared__ unsigned short     wl[NSEG];        // 2 KB
  __shared__ int                s_cnt[2];
  // total ~150.2 KB

  // ---- init A: per-seg bbox -> staging (cen in cand, ext in dmin), pack ---
  for (int r = 0; r < 32; ++r) {
    const int seg = r * 32 + hw;
    const int i = seg * 32 + hl;
    const float4 q = P[i];
    float xl = q.x, xh = q.x, yl = q.y, yh = q.y, zl = q.z, zh = q.z;
    unsigned k = ((unsigned)__float_as_int(q.w) << 15) | (unsigned)i;
#pragma unroll
    for (int off = 16; off > 0; off >>= 1) {
      xl = fminf(xl, __shfl_xor(xl, off)); xh = fmaxf(xh, __shfl_xor(xh, off));
      yl = fminf(yl, __shfl_xor(yl, off)); yh = fmaxf(yh, __shfl_xor(yh, off));
      zl = fminf(zl, __shfl_xor(zl, off)); zh = fmaxf(zh, __shfl_xor(zh, off));
      k  = min(k, (unsigned)__shfl_xor((int)k, off));
    }
    if (hl == 0) {
      const float cxm = 0.5f * (xl + xh);
      const float cym = 0.5f * (yl + yh);
      const float czm = 0.5f * (zl + zh);
      cand[0][seg] = cxm; cand[1][seg] = cym; cand[2][seg] = czm;
      // extent +2ulp nudge => provably enclosing despite center rounding
      dmin[seg]            = __uint_as_float(__float_as_uint(fmaxf(xh - cxm, cxm - xl)) + 2);
      dmin[NSEG + seg]     = __uint_as_float(__float_as_uint(fmaxf(yh - cym, cym - yl)) + 2);
      dmin[2 * NSEG + seg] = __uint_as_float(__float_as_uint(fmaxf(zh - czm, czm - zl)) + 2);
      pack[seg] = ((unsigned long long)__float_as_uint(1e10f) << 32) |
                  (unsigned long long)(0x3FFFFFFFu - k);
    }
  }
  __syncthreads();

  // ---- init B: staging -> owner-thread registers; candidate coords ----
  const float cenr0 = cand[0][t], cenr1 = cand[1][t], cenr2 = cand[2][t];
  const float extr0 = dmin[t], extr1 = dmin[NSEG + t], extr2 = dmin[2 * NSEG + t];
  const unsigned k0 = 0x3FFFFFFFu - (unsigned)(pack[t] & 0x3FFFFFFFull);
  const float4 qc = P[(int)(k0 & 0x7FFFu)];      // seg's initial candidate
  __syncthreads();                                // staging reads complete

  cand[0][t] = qc.x; cand[1][t] = qc.y; cand[2][t] = qc.z;
  for (int k = 0; k < 32; ++k) dmin[k * NTH + t] = 1e10f;   // real dmin init
  if (t == 0) { s_cnt[0] = 0; s_cnt[1] = 0; }
  __syncthreads();

  // initial stage-1 so step 0's combine sees valid s_red[0]
  if (t < 512) {
    unsigned long long p = u64max(pack[t], pack[t + 512]);
#pragma unroll
    for (int off = 32; off > 0; off >>= 1) p = u64max(p, shflxor_u64(p, off));
    if (lane == 0) s_red[0][w] = p;
  }
  __syncthreads();

  for (int s = 0; s < NPOINT; ++s) {
    // ---- combine + winner centroid (LDS broadcast) ----
    unsigned long long p = s_red[s & 1][0];
#pragma unroll
    for (int j = 1; j < 8; ++j) p = u64max(p, s_red[s & 1][j]);
    const unsigned kwin = 0x3FFFFFFFu - (unsigned)(p & 0x3FFFFFFFu);
    const int far  = (int)(kwin >> 15);
    const int segw = (int)((kwin & 0x7FFFu) >> 5);
    const float cx = cand[0][segw], cy = cand[1][segw], cz = cand[2][segw];

    if (t == 0) fps_idx[b * NPOINT + s] = far;
    if (t == NTH - 1) s_cnt[(s + 1) & 1] = 0;

    // ---- phase B: predicate from REGISTERS (seg = t) + compact ----
    {
      const float cm = __uint_as_float((unsigned)(pack[t] >> 32));
      const float ddx = fmaxf(fabsf(cx - cenr0) - extr0, 0.0f);
      const float ddy = fmaxf(fabsf(cy - cenr1) - extr1, 0.0f);
      const float ddz = fmaxf(fabsf(cz - cenr2) - extr2, 0.0f);
      const float r2 = ddx * ddx + ddy * ddy + ddz * ddz;
      const bool need = !(r2 * 0.999f > cm);
      const unsigned long long bal = __ballot(need);
      int wb = 0;
      if (lane == 0 && bal != 0ull)
        wb = atomicAdd(&s_cnt[s & 1], (int)__popcll(bal));
      wb = __shfl(wb, 0);
      if (need) {
        const unsigned long long ltm = (1ull << lane) - 1ull;
        wl[wb + (int)__popcll(bal & ltm)] = (unsigned short)t;
      }
    }
    __syncthreads();                                          // B1

    // ---- phase C: 32 half-waves co-scan needy segs; 4/2/1-way tiers ----
    const int nC = s_cnt[s & 1];
    int e = hw;
#define SEG_BODY(SEGV, PKV)                                                    \
      const int i_##PKV = (SEGV) * 32 + hl;                                    \
      const float4 q_##PKV = P[i_##PKV];                                       \
      const float dm_##PKV = dmin[i_##PKV];                                    \
      const float dx_##PKV = q_##PKV.x - cx, dy_##PKV = q_##PKV.y - cy,        \
                  dz_##PKV = q_##PKV.z - cz;                                   \
      const float d_##PKV = __builtin_fmaf(dz_##PKV, dz_##PKV,                 \
          __builtin_fmaf(dy_##PKV, dy_##PKV, dx_##PKV * dx_##PKV));            \
      const float nd_##PKV = fminf(dm_##PKV, d_##PKV);                         \
      dmin[i_##PKV] = nd_##PKV;                                                \
      const unsigned kk_##PKV =                                                \
          ((unsigned)__float_as_int(q_##PKV.w) << 15) | (unsigned)i_##PKV;     \
      unsigned long long PKV =                                                 \
          ((unsigned long long)__float_as_uint(nd_##PKV) << 32) |              \
          (unsigned long long)(0x3FFFFFFFu - kk_##PKV);                        \
      const unsigned long long PKV##0 = PKV;

    for (; e + 96 < nC; e += 128) {
      const int sA = (int)wl[e], sB = (int)wl[e + 32],
                sC = (int)wl[e + 64], sD = (int)wl[e + 96];
      SEG_BODY(sA, pA) SEG_BODY(sB, pB) SEG_BODY(sC, pC) SEG_BODY(sD, pD)
#pragma unroll
      for (int off = 16; off > 0; off >>= 1) {
        pA = u64max(pA, shflxor_u64(pA, off));
        pB = u64max(pB, shflxor_u64(pB, off));
        pC = u64max(pC, shflxor_u64(pC, off));
        pD = u64max(pD, shflxor_u64(pD, off));
      }
      if (hl == 0) { pack[sA]=pA; pack[sB]=pB; pack[sC]=pC; pack[sD]=pD; }
      if (pA0 == pA) { cand[0][sA]=q_pA.x; cand[1][sA]=q_pA.y; cand[2][sA]=q_pA.z; }
      if (pB0 == pB) { cand[0][sB]=q_pB.x; cand[1][sB]=q_pB.y; cand[2][sB]=q_pB.z; }
      if (pC0 == pC) { cand[0][sC]=q_pC.x; cand[1][sC]=q_pC.y; cand[2][sC]=q_pC.z; }
      if (pD0 == pD) { cand[0][sD]=q_pD.x; cand[1][sD]=q_pD.y; cand[2][sD]=q_pD.z; }
    }
    for (; e + 32 < nC; e += 64) {
      const int sA = (int)wl[e], sB = (int)wl[e + 32];
      SEG_BODY(sA, pA) SEG_BODY(sB, pB)
#pragma unroll
      for (int off = 16; off > 0; off >>= 1) {
        pA = u64max(pA, shflxor_u64(pA, off));
        pB = u64max(pB, shflxor_u64(pB, off));
      }
      if (hl == 0) { pack[sA] = pA; pack[sB] = pB; }
      if (pA0 == pA) { cand[0][sA]=q_pA.x; cand[1][sA]=q_pA.y; cand[2][sA]=q_pA.z; }
      if (pB0 == pB) { cand[0][sB]=q_pB.x; cand[1][sB]=q_pB.y; cand[2][sB]=q_pB.z; }
    }
    for (; e < nC; e += 32) {
      const int sA = (int)wl[e];
      SEG_BODY(sA, pA)
#pragma unroll
      for (int off = 16; off > 0; off >>= 1) pA = u64max(pA, shflxor_u64(pA, off));
      if (hl == 0) pack[sA] = pA;
      if (pA0 == pA) { cand[0][sA]=q_pA.x; cand[1][sA]=q_pA.y; cand[2][sA]=q_pA.z; }
    }
#undef SEG_BODY
    __syncthreads();                                          // B2

    // ---- stage 1: 512 threads reduce 1024 packs -> s_red[(s+1)&1][8] ----
    if (t < 512) {
      unsigned long long pk = u64max(pack[t], pack[t + 512]);
#pragma unroll
      for (int off = 32; off > 0; off >>= 1) pk = u64max(pk, shflxor_u64(pk, off));
      if (lane == 0) s_red[(s + 1) & 1][w] = pk;
    }
    __syncthreads();                                          // B3
  }
}

// ---------------------------------------------------------------------------
// Gather: [B][NPOINT][3] then [B][NPOINT][128], concatenated flat.
// ---------------------------------------------------------------------------
__global__ __launch_bounds__(256) void gather_kernel(
    const float* __restrict__ xyz, const float* __restrict__ feat,
    const int* __restrict__ fps_idx, float* __restrict__ out) {
  const int lane = threadIdx.x & 31;
  const int sub  = threadIdx.x >> 5;
  const int row  = blockIdx.x * 8 + sub;
  const int b    = row >> 11;
  const int src  = fps_idx[row];

  const float4* __restrict__ f =
      reinterpret_cast<const float4*>(feat + ((size_t)b * NPTS + src) * C_FEAT);
  float4* __restrict__ o =
      reinterpret_cast<float4*>(out + (size_t)BATCH * NPOINT * 3 +
                                (size_t)row * C_FEAT);
  o[lane] = f[lane];
  if (lane < 3) {
    out[(size_t)row * 3 + lane] = xyz[((size_t)b * NPTS + src) * 3 + lane];
  }
}

extern "C" void kernel_launch(void* const* d_in, const int* in_sizes, int n_in,
                              void* d_out, int out_size, void* d_ws, size_t ws_size,
                              hipStream_t stream) {
  (void)in_sizes; (void)n_in; (void)out_size; (void)ws_size;
  const float* xyz  = (const float*)d_in[0];
  const float* feat = (const float*)d_in[1];
  float* out = (float*)d_out;

  char* ws = (char*)d_ws;
  int*    fps_idx = (int*)ws;                     // 128 KB @ 0
  float4* pts     = (float4*)(ws + (1u << 20));   // 8 MB  @ 1MB

  sort_kernel<<<BATCH, NTH, 0, stream>>>(xyz, pts);
  fps_kernel<<<BATCH, NTH, 0, stream>>>(pts, fps_idx);
  gather_kernel<<<(BATCH * NPOINT) / 8, 256, 0, stream>>>(xyz, feat, fps_idx, out);
}

// Round 22
// 3827.182 us; speedup vs baseline: 1.0236x; 1.0236x over previous
//
#include <hip/hip_runtime.h>

#define BATCH   16
#define NPTS    32768
#define NPOINT  2048
#define C_FEAT  128
#define NSEG    1024          // 32 Morton-consecutive points per segment
#define NTH     1024
#define NW      16

// ===========================================================================
// Round 22 = REVERT to round 19 verbatim (best proven: 3.830ms, absmax 0).
// r20/r21 (register bboxes + cand[] centroid + 4-way unroll) were neutral to
// -2.3% => the 3-barrier work-shared skeleton is at its latency floor:
// per step ~1.85us of serial dependency (combine -> predicate -> B1 ->
// L2-load+LDS-RMW+reduce -> B2 -> stage-1 -> B3) x 2048 inherently serial
// FPS steps. Not memory- or compute-bound (HBM 0.01%, VALU 2.2%).
// Design recap: work-shared lazy FPS. Morton sort -> 32-pt segs; per-seg
// bbox (f32 center + bf16-up extent) + memoized (cmax, argkey) u64 packs;
// needy segs compacted to a worklist scanned by ALL 32 half-waves (TLP hides
// L2 latency -- the r16 breakthrough); two-stage pack reduce.
// Exactness: skip seg only if r2*0.999 > cmax with provably-enclosing bbox
// (+2ulp nudge, bf16 round-up ext; margin >> fp error) => skipped dmin bits
// unchanged; update = r7-VERIFIED fmaf(dz,dz,fmaf(dy,dy,dx*dx)) (the
// reference's exact fp32 pipeline); u64 pack-max = (max cmax, tie -> min
// ORIGINAL index) == np.argmax first-occurrence; scatter-order-independent.
// ws: [fps_idx 128KB @0][pts 8MB @1MB]
// ===========================================================================

__device__ __forceinline__ unsigned part4(unsigned v) {
  return (v & 1u) | ((v & 2u) << 2) | ((v & 4u) << 4) | ((v & 8u) << 6);
}
__device__ __forceinline__ int morton(float x, float y, float z) {
  const unsigned qx = (unsigned)min(15, max(0, (int)((x + 4.0f) * 2.0f)));
  const unsigned qy = (unsigned)min(15, max(0, (int)((y + 4.0f) * 2.0f)));
  const unsigned qz = (unsigned)min(15, max(0, (int)((z + 4.0f) * 2.0f)));
  return (int)(part4(qx) | (part4(qy) << 1) | (part4(qz) << 2));
}

__device__ __forceinline__ unsigned long long u64max(unsigned long long a,
                                                     unsigned long long b) {
  return a > b ? a : b;
}
__device__ __forceinline__ unsigned long long shflxor_u64(
    unsigned long long v, int off) {
  const unsigned lo = (unsigned)v, hi = (unsigned)(v >> 32);
  const unsigned olo = (unsigned)__shfl_xor((int)lo, off);
  const unsigned ohi = (unsigned)__shfl_xor((int)hi, off);
  return ((unsigned long long)ohi << 32) | olo;
}
// bf16 round-UP for positive floats (conservative extent)
__device__ __forceinline__ unsigned short bfup(float e) {
  const unsigned u = __float_as_uint(e);
  unsigned short b = (unsigned short)(u >> 16);
  if (__uint_as_float(((unsigned)b) << 16) < e) ++b;
  return b;
}

// ---------------------------------------------------------------------------
// Morton counting sort: pts[pos] = (x,y,z,bitcast(origidx)) in sorted order.
// ---------------------------------------------------------------------------
__global__ __launch_bounds__(NTH) void sort_kernel(
    const float* __restrict__ xyz, float4* __restrict__ pts) {
  const int b = blockIdx.x, t = threadIdx.x, lane = t & 63;
  const float* __restrict__ base = xyz + (size_t)b * NPTS * 3;
  __shared__ unsigned bins[4096];
  __shared__ unsigned wsum[NW];

  for (int i = t; i < 4096; i += NTH) bins[i] = 0u;
  __syncthreads();
  for (int k = 0; k < 32; ++k) {
    const int p = k * NTH + t;
    atomicAdd(&bins[morton(base[p*3], base[p*3+1], base[p*3+2])], 1u);
  }
  __syncthreads();

  unsigned c0 = bins[4*t], c1 = bins[4*t+1], c2 = bins[4*t+2], c3 = bins[4*t+3];
  const unsigned mysum = c0 + c1 + c2 + c3;
  unsigned acc = mysum;
#pragma unroll
  for (int d = 1; d < 64; d <<= 1) {
    unsigned n = __shfl_up(acc, d);
    if (lane >= d) acc += n;
  }
  if (lane == 63) wsum[t >> 6] = acc;
  __syncthreads();
  unsigned woff = 0;
  for (int w = 0; w < (t >> 6); ++w) woff += wsum[w];
  unsigned run = woff + acc - mysum;
  bins[4*t]   = run; run += c0;
  bins[4*t+1] = run; run += c1;
  bins[4*t+2] = run; run += c2;
  bins[4*t+3] = run;
  __syncthreads();

  float4* __restrict__ pb = pts + (size_t)b * NPTS;
  for (int k = 0; k < 32; ++k) {
    const int p = k * NTH + t;
    const float x = base[p*3], y = base[p*3+1], z = base[p*3+2];
    const unsigned pos = atomicAdd(&bins[morton(x, y, z)], 1u);
    pb[pos] = make_float4(x, y, z, __int_as_float(p));
  }
}

// ---------------------------------------------------------------------------
// Work-shared lazy FPS, 32-pt half-wave segments. One block per batch.
// ---------------------------------------------------------------------------
__global__ __launch_bounds__(NTH) void fps_kernel(
    const float4* __restrict__ pts_g, int* __restrict__ fps_idx) {
  const int b = blockIdx.x, t = threadIdx.x, lane = t & 63, w = t >> 6;
  const int hw = t >> 5, hl = t & 31;            // 32 half-waves of 32 lanes
  const float4* __restrict__ P = pts_g + (size_t)b * NPTS;

  __shared__ float              dmin[NPTS];      // 128 KB
  __shared__ unsigned long long pack[NSEG];      // 8 KB
  __shared__ float              cenx[NSEG], ceny[NSEG], cenz[NSEG];  // 12 KB
  __shared__ unsigned short     extx[NSEG], exty[NSEG], extz[NSEG];  // 6 KB
  __shared__ unsigned long long s_red[2][8];     // 128 B
  __shared__ unsigned short     wl[NSEG];        // 2 KB
  __shared__ int                s_cnt[2];

  // ---- init: dmin, per-seg bbox (center + bf16-up extent), pack ----
  for (int r = 0; r < 32; ++r) {
    const int seg = r * 32 + hw;
    const int i = seg * 32 + hl;
    const float4 q = P[i];
    dmin[i] = 1e10f;
    float xl = q.x, xh = q.x, yl = q.y, yh = q.y, zl = q.z, zh = q.z;
    unsigned k = ((unsigned)__float_as_int(q.w) << 15) | (unsigned)i;
#pragma unroll
    for (int off = 16; off > 0; off >>= 1) {
      xl = fminf(xl, __shfl_xor(xl, off)); xh = fmaxf(xh, __shfl_xor(xh, off));
      yl = fminf(yl, __shfl_xor(yl, off)); yh = fmaxf(yh, __shfl_xor(yh, off));
      zl = fminf(zl, __shfl_xor(zl, off)); zh = fmaxf(zh, __shfl_xor(zh, off));
      k  = min(k, (unsigned)__shfl_xor((int)k, off));
    }
    if (hl == 0) {
      const float cxm = 0.5f * (xl + xh);
      const float cym = 0.5f * (yl + yh);
      const float czm = 0.5f * (zl + zh);
      // extent: f32 +2ulp nudge then bf16 round-up => provably enclosing
      float ex = fmaxf(xh - cxm, cxm - xl);
      float ey = fmaxf(yh - cym, cym - yl);
      float ez = fmaxf(zh - czm, czm - zl);
      ex = __uint_as_float(__float_as_uint(ex) + 2);
      ey = __uint_as_float(__float_as_uint(ey) + 2);
      ez = __uint_as_float(__float_as_uint(ez) + 2);
      cenx[seg] = cxm; ceny[seg] = cym; cenz[seg] = czm;
      extx[seg] = bfup(ex); exty[seg] = bfup(ey); extz[seg] = bfup(ez);
      pack[seg] = ((unsigned long long)__float_as_uint(1e10f) << 32) |
                  (unsigned long long)(0x3FFFFFFFu - k);
    }
  }
  if (t == 0) { s_cnt[0] = 0; s_cnt[1] = 0; }
  __syncthreads();

  // initial stage-1 so step 0's combine sees valid s_red[0]
  if (t < 512) {
    unsigned long long p = u64max(pack[t], pack[t + 512]);
#pragma unroll
    for (int off = 32; off > 0; off >>= 1) p = u64max(p, shflxor_u64(p, off));
    if (lane == 0) s_red[0][w] = p;
  }
  __syncthreads();

  for (int s = 0; s < NPOINT; ++s) {
    // ---- combine + winner centroid (broadcast L2 load) ----
    unsigned long long p = s_red[s & 1][0];
#pragma unroll
    for (int j = 1; j < 8; ++j) p = u64max(p, s_red[s & 1][j]);
    const unsigned kwin = 0x3FFFFFFFu - (unsigned)(p & 0x3FFFFFFFu);
    const int far = (int)(kwin >> 15);
    const float4 qn = P[(int)(kwin & 0x7FFFu)];
    const float cx = qn.x, cy = qn.y, cz = qn.z;

    if (t == 0) fps_idx[b * NPOINT + s] = far;
    if (t == NTH - 1) s_cnt[(s + 1) & 1] = 0;

    // ---- phase B: predicate on ALL 1024 threads (seg = t) + compact ----
    {
      const unsigned long long pk = pack[t];
      const float cm = __uint_as_float((unsigned)(pk >> 32));
      const float ex = __uint_as_float(((unsigned)extx[t]) << 16);
      const float ey = __uint_as_float(((unsigned)exty[t]) << 16);
      const float ez = __uint_as_float(((unsigned)extz[t]) << 16);
      const float ddx = fmaxf(fabsf(cx - cenx[t]) - ex, 0.0f);
      const float ddy = fmaxf(fabsf(cy - ceny[t]) - ey, 0.0f);
      const float ddz = fmaxf(fabsf(cz - cenz[t]) - ez, 0.0f);
      const float r2 = ddx * ddx + ddy * ddy + ddz * ddz;
      const bool need = !(r2 * 0.999f > cm);
      const unsigned long long bal = __ballot(need);
      int wb = 0;
      if (lane == 0 && bal != 0ull)
        wb = atomicAdd(&s_cnt[s & 1], (int)__popcll(bal));
      wb = __shfl(wb, 0);
      if (need) {
        const unsigned long long ltm = (1ull << lane) - 1ull;
        wl[wb + (int)__popcll(bal & ltm)] = (unsigned short)t;
      }
    }
    __syncthreads();                                          // B1

    // ---- phase C: 32 half-waves co-scan needy segs; 2-way unrolled ----
    const int C = s_cnt[s & 1];
    int e = hw;
    for (; e + 32 < C; e += 64) {
      const int segA = (int)wl[e], segB = (int)wl[e + 32];
      const int iA = segA * 32 + hl, iB = segB * 32 + hl;
      const float4 qA = P[iA];
      const float4 qB = P[iB];
      const float dmA = dmin[iA], dmB = dmin[iB];
      const float dxA = qA.x - cx, dyA = qA.y - cy, dzA = qA.z - cz;
      const float dxB = qB.x - cx, dyB = qB.y - cy, dzB = qB.z - cz;
      // EXACT reference pipeline (verified round 7):
      const float dA = __builtin_fmaf(dzA, dzA, __builtin_fmaf(dyA, dyA, dxA*dxA));
      const float dB = __builtin_fmaf(dzB, dzB, __builtin_fmaf(dyB, dyB, dxB*dxB));
      const float ndA = fminf(dmA, dA), ndB = fminf(dmB, dB);
      dmin[iA] = ndA; dmin[iB] = ndB;
      const unsigned kA = ((unsigned)__float_as_int(qA.w) << 15) | (unsigned)iA;
      const unsigned kB = ((unsigned)__float_as_int(qB.w) << 15) | (unsigned)iB;
      unsigned long long pA = ((unsigned long long)__float_as_uint(ndA) << 32) |
                              (unsigned long long)(0x3FFFFFFFu - kA);
      unsigned long long pB = ((unsigned long long)__float_as_uint(ndB) << 32) |
                              (unsigned long long)(0x3FFFFFFFu - kB);
#pragma unroll
      for (int off = 16; off > 0; off >>= 1) {
        pA = u64max(pA, shflxor_u64(pA, off));
        pB = u64max(pB, shflxor_u64(pB, off));
      }
      if (hl == 0) { pack[segA] = pA; pack[segB] = pB; }
    }
    for (; e < C; e += 32) {
      const int seg = (int)wl[e];
      const int i = seg * 32 + hl;
      const float4 q = P[i];
      const float dx = q.x - cx, dy = q.y - cy, dz = q.z - cz;
      const float d = __builtin_fmaf(dz, dz, __builtin_fmaf(dy, dy, dx * dx));
      const float nd = fminf(dmin[i], d);
      dmin[i] = nd;
      const unsigned k = ((unsigned)__float_as_int(q.w) << 15) | (unsigned)i;
      unsigned long long pk = ((unsigned long long)__float_as_uint(nd) << 32) |
                              (unsigned long long)(0x3FFFFFFFu - k);
#pragma unroll
      for (int off = 16; off > 0; off >>= 1) pk = u64max(pk, shflxor_u64(pk, off));
      if (hl == 0) pack[seg] = pk;
    }
    __syncthreads();                                          // B2

    // ---- stage 1: 512 threads reduce 1024 packs -> s_red[(s+1)&1][8] ----
    if (t < 512) {
      unsigned long long pk = u64max(pack[t], pack[t + 512]);
#pragma unroll
      for (int off = 32; off > 0; off >>= 1) pk = u64max(pk, shflxor_u64(pk, off));
      if (lane == 0) s_red[(s + 1) & 1][w] = pk;
    }
    __syncthreads();                                          // B3
  }
}

// ---------------------------------------------------------------------------
// Gather: [B][NPOINT][3] then [B][NPOINT][128], concatenated flat.
// ---------------------------------------------------------------------------
__global__ __launch_bounds__(256) void gather_kernel(
    const float* __restrict__ xyz, const float* __restrict__ feat,
    const int* __restrict__ fps_idx, float* __restrict__ out) {
  const int lane = threadIdx.x & 31;
  const int sub  = threadIdx.x >> 5;
  const int row  = blockIdx.x * 8 + sub;
  const int b    = row >> 11;
  const int src  = fps_idx[row];

  const float4* __restrict__ f =
      reinterpret_cast<const float4*>(feat + ((size_t)b * NPTS + src) * C_FEAT);
  float4* __restrict__ o =
      reinterpret_cast<float4*>(out + (size_t)BATCH * NPOINT * 3 +
                                (size_t)row * C_FEAT);
  o[lane] = f[lane];
  if (lane < 3) {
    out[(size_t)row * 3 + lane] = xyz[((size_t)b * NPTS + src) * 3 + lane];
  }
}

extern "C" void kernel_launch(void* const* d_in, const int* in_sizes, int n_in,
                              void* d_out, int out_size, void* d_ws, size_t ws_size,
                              hipStream_t stream) {
  (void)in_sizes; (void)n_in; (void)out_size; (void)ws_size;
  const float* xyz  = (const float*)d_in[0];
  const float* feat = (const float*)d_in[1];
  float* out = (float*)d_out;

  char* ws = (char*)d_ws;
  int*    fps_idx = (int*)ws;                     // 128 KB @ 0
  float4* pts     = (float4*)(ws + (1u << 20));   // 8 MB  @ 1MB

  sort_kernel<<<BATCH, NTH, 0, stream>>>(xyz, pts);
  fps_kernel<<<BATCH, NTH, 0, stream>>>(pts, fps_idx);
  gather_kernel<<<(BATCH * NPOINT) / 8, 256, 0, stream>>>(xyz, feat, fps_idx, out);
}